// Round 7
// baseline (32404.251 us; speedup 1.0000x reference)
//
#include <hip/hip_runtime.h>
#include <hip/hip_bf16.h>
#include <math.h>

// DARQN: conv×3 -> per-step additive attention + LSTM scan (T=2048) -> q head.
// R7: ONE inter-WG hop per step. Every WG computes the FULL attention (all 49
// rows -> full ctx) redundantly — the ctx-exchange hop is gone. Only h (8 WGs
// × 32 dims) is exchanged, using R2's proven drain->flag->gather protocol.
// A and vecs stored bf16 (halves stream; LIC absorbs the 8x redundant reads).
// All scan weights register-resident as MFMA B-frags (full W2 per WG).

#define T_FRAMES 2048
#define NI 49
#define HID 256
#define NA 18
#define NWG 8
#define POLL_MAX 2000000

typedef __bf16 v8bf __attribute__((ext_vector_type(8)));
typedef float v4f __attribute__((ext_vector_type(4)));

// ---------------- workspace layout (bytes) ----------------
// fm1 region (104,857,600 B) is dead after conv2; A_bf16 + vecs_bf16 alias it.
static constexpr size_t OFF_ABF   = 0;                  // bf16 A [2048,49,256] (51,380,224)
static constexpr size_t OFF_VBF   = 51380224;           // bf16 vecs [2048,49,256] (51,380,224)
static constexpr size_t OFF_FM1   = 0;                  // f32 fm1 [2048,32,20,20] (conv1 out)
static constexpr size_t OFF_FM2   = 104857600;          // f32 fm2 [2048,64,9,9]; comm aliases after conv3
static constexpr size_t OFF_VECS  = 147324928;          // f32 vecs [2048,49,256] (aprep input)
static constexpr size_t OFF_W2B   = 250085376;          // bf16 256*256
static constexpr size_t OFF_WIHB  = OFF_W2B  + 131072;  // bf16 1024*256
static constexpr size_t OFF_WHHB  = OFF_WIHB + 524288;  // bf16 1024*256
static constexpr size_t OFF_W1T   = OFF_WHHB + 524288;  // f32 256*256
// comm block aliases fm2 region (valid after conv3 consumed fm2):
static constexpr size_t OFF_HBUF  = OFF_FM2;            // f32[256]
static constexpr size_t OFF_FLH   = OFF_FM2 + 1024;     // u32[8*32]

// ---------------- weight prep ----------------
__global__ void prep_weights(const float* __restrict__ w2, const float* __restrict__ wih,
                             const float* __restrict__ whh, const float* __restrict__ w1,
                             __bf16* w2b, __bf16* wihb, __bf16* whhb, float* w1t) {
  int idx = blockIdx.x * 256 + threadIdx.x;
  int stride = gridDim.x * 256;
  for (int i = idx; i < 65536; i += stride) w2b[i] = (__bf16)w2[i];
  for (int i = idx; i < 262144; i += stride) wihb[i] = (__bf16)wih[i];
  for (int i = idx; i < 262144; i += stride) whhb[i] = (__bf16)whh[i];
  for (int i = idx; i < 65536; i += stride) {
    int r = i >> 8, c = i & 255;
    w1t[c * 256 + r] = w1[i];
  }
}

// ---------------- conv1: [T,1,84,84] -> [T,32,20,20], k8 s4 ----------------
__global__ void conv1_k(const float* __restrict__ x, const float* __restrict__ w,
                        const float* __restrict__ b, float* __restrict__ y) {
  int idx = blockIdx.x * 256 + threadIdx.x;
  if (idx >= T_FRAMES * 32 * 20 * 20) return;
  int xx = idx % 20, yy = (idx / 20) % 20, o = (idx / 400) % 32, t = idx / 12800;
  const float* xp = x + t * 7056 + yy * 4 * 84 + xx * 4;
  const float* wp = w + o * 64;
  float acc = b[o];
  #pragma unroll
  for (int ky = 0; ky < 8; ky++)
    #pragma unroll
    for (int kx = 0; kx < 8; kx++)
      acc += xp[ky * 84 + kx] * wp[ky * 8 + kx];
  y[idx] = fmaxf(acc, 0.f);
}

// ---------------- conv2: [T,32,20,20] -> [T,64,9,9], k4 s2 ----------------
__global__ __launch_bounds__(256) void conv2_k(const float* __restrict__ fm1, const float* __restrict__ w,
                                               const float* __restrict__ b, float* __restrict__ fm2) {
  __shared__ float xs[32 * 400];
  int t = blockIdx.x, tid = threadIdx.x;
  for (int i = tid; i < 12800; i += 256) xs[i] = fm1[t * 12800 + i];
  __syncthreads();
  int o = tid >> 2, q = tid & 3;
  int p0 = q * 21, p1 = (p0 + 21 < 81) ? p0 + 21 : 81;
  int ob[21];
  #pragma unroll
  for (int i2 = 0; i2 < 21; i2++) {
    int p = p0 + i2; if (p > 80) p = 80;
    int yy = p / 9, xx2 = p - yy * 9;
    ob[i2] = yy * 40 + xx2 * 2;
  }
  float acc[21];
  #pragma unroll
  for (int i2 = 0; i2 < 21; i2++) acc[i2] = 0.f;
  for (int c = 0; c < 32; c++) {
    int cbase = c * 400;
    for (int ky = 0; ky < 4; ky++)
      for (int kx = 0; kx < 4; kx++) {
        float wgt = w[((o * 32 + c) * 4 + ky) * 4 + kx];
        int kyo = ky * 20 + kx;
        #pragma unroll
        for (int i2 = 0; i2 < 21; i2++)
          acc[i2] += wgt * xs[cbase + ob[i2] + kyo];
      }
  }
  float bo = b[o];
  #pragma unroll
  for (int i2 = 0; i2 < 21; i2++) {
    int p = p0 + i2;
    if (p < p1) fm2[t * 5184 + o * 81 + p] = fmaxf(acc[i2] + bo, 0.f);
  }
}

// ---------------- conv3: [T,64,9,9] -> vecs f32 + bf16, k3 s1 ----------------
__global__ __launch_bounds__(256) void conv3_k(const float* __restrict__ fm2, const float* __restrict__ w,
                                               const float* __restrict__ b, float* __restrict__ vecs,
                                               __bf16* __restrict__ vb) {
  __shared__ float xs[64 * 81];
  __shared__ float ws4[256][37];
  int t = blockIdx.x, tid = threadIdx.x;
  for (int i = tid; i < 64 * 81; i += 256) xs[i] = fm2[t * 5184 + i];
  float acc[49];
  #pragma unroll
  for (int i = 0; i < 49; i++) acc[i] = 0.f;
  for (int c0 = 0; c0 < 64; c0 += 4) {
    __syncthreads();
    for (int i = tid; i < 256 * 36; i += 256) {
      int oo = i / 36, j = i - oo * 36;
      ws4[oo][j] = w[oo * 576 + c0 * 9 + j];
    }
    __syncthreads();
    for (int cc = 0; cc < 4; cc++)
      for (int ky = 0; ky < 3; ky++)
        for (int kx = 0; kx < 3; kx++) {
          float wgt = ws4[tid][cc * 9 + ky * 3 + kx];
          const float* xp = &xs[(c0 + cc) * 81 + ky * 9 + kx];
          #pragma unroll
          for (int yy = 0; yy < 7; yy++)
            #pragma unroll
            for (int xx = 0; xx < 7; xx++)
              acc[yy * 7 + xx] += wgt * xp[yy * 9 + xx];
        }
  }
  float bo = b[tid];
  for (int i = 0; i < 49; i++) {
    float val = fmaxf(acc[i] + bo, 0.f);
    vecs[(t * 49 + i) * 256 + tid] = val;
    vb[(t * 49 + i) * 256 + tid] = (__bf16)val;
  }
}

// ---------------- A[t,i,:] = vecs[t,i,:] @ W1^T + b1  (bf16 out) ----------------
__global__ __launch_bounds__(256) void aprep_k(const float* __restrict__ vecs, const float* __restrict__ w1t,
                                               const float* __restrict__ b1, __bf16* __restrict__ Ab) {
  __shared__ float vs[49][256];
  int t = blockIdx.x, tid = threadIdx.x;
  for (int i = tid; i < 49 * 256; i += 256) vs[i >> 8][i & 255] = vecs[t * 12544 + i];
  __syncthreads();
  float acc[49];
  #pragma unroll
  for (int i = 0; i < 49; i++) acc[i] = 0.f;
  for (int k = 0; k < 256; k++) {
    float wgt = w1t[k * 256 + tid];
    #pragma unroll
    for (int i = 0; i < 49; i++) acc[i] += vs[i][k] * wgt;
  }
  float bb = b1[tid];
  for (int i = 0; i < 49; i++) Ab[(t * 49 + i) * 256 + tid] = (__bf16)(acc[i] + bb);
}

// ---------------- init comm (after conv3: aliases fm2) ----------------
__global__ void init_comm(unsigned* flh) {
  int idx = threadIdx.x;
  if (idx < NWG * 32) flh[idx] = 0u;
}

__device__ __forceinline__ float tanh_fast(float x) {
  float e = __expf(2.f * x);
  return 1.f - 2.f / (e + 1.f);
}

// ---------------- scan: 8 WGs, redundant full attention, single h-hop ----------------
__global__ __launch_bounds__(256, 1) void scan_k(
    const __bf16* __restrict__ Abf, const __bf16* __restrict__ vbf,
    const __bf16* __restrict__ w2b, const __bf16* __restrict__ wihb, const __bf16* __restrict__ whhb,
    const float* __restrict__ b2g, const float* __restrict__ bihg, const float* __restrict__ bhhg,
    const float* __restrict__ qw, const float* __restrict__ qb,
    float* hbuf, unsigned* flh, float* out) {
  __shared__ __attribute__((aligned(16))) __bf16 Ss[64][264];  // s rows (49 live, rest zero)
  __shared__ __attribute__((aligned(16))) __bf16 Vs[49][264];  // v rows bf16
  __shared__ float Wt[49][257];    // logits (257: quad-spread banks)
  __shared__ float ctxp[4][256];   // per-wave ctx partials
  __shared__ float hs[HID];
  __shared__ __attribute__((aligned(16))) __bf16 hbf[HID];
  __shared__ __attribute__((aligned(16))) __bf16 cxbf[HID];
  __shared__ float b2s[HID];
  __shared__ float gb[4][32];

  const int w = blockIdx.x;
  const int tid = threadIdx.x;
  const int lane = tid & 63;
  const int wv = tid >> 6;          // wave 0..3 (= LSTM gate id)
  const int quad = lane >> 4;
  const int l15 = lane & 15;
  const int r8 = tid >> 5;          // 0..7: loader row-group (7 rows each)
  const int c32 = tid & 31;         // loader col-block (8 cols)
  int dead = 0;

  for (int i = tid; i < 64 * 264; i += 256) (&Ss[0][0])[i] = (__bf16)0.f;
  b2s[tid] = b2g[tid];
  hs[tid] = 0.f;
  hbf[tid] = (__bf16)0.f;
  float cbias[4];
  if (tid < 32) {
    #pragma unroll
    for (int g = 0; g < 4; g++) {
      int row = 256 * g + 32 * w + tid;
      cbias[g] = bihg[row] + bhhg[row];
    }
  }
  float creg = 0.f;  // cell state: tid<32 owns dim 32*w+tid

  // ---- register-resident MFMA B-fragments ----
  v8bf BW2[4][8];  // FULL W2 per WG: wave wv owns logit cols wv*64 + ntl*16 + l15
  #pragma unroll
  for (int ntl = 0; ntl < 4; ntl++) {
    const int row = wv * 64 + ntl * 16 + l15;
    #pragma unroll
    for (int k = 0; k < 8; k++)
      BW2[ntl][k] = *(const v8bf*)(w2b + row * 256 + k * 32 + quad * 8);
  }
  v8bf BIH[2][8], BHH[2][8];  // LSTM slice: gate wv, dims 32*w + nt*16 + l15
  #pragma unroll
  for (int nt = 0; nt < 2; nt++) {
    const int row = 256 * wv + 32 * w + nt * 16 + l15;
    #pragma unroll
    for (int k = 0; k < 8; k++) {
      BIH[nt][k] = *(const v8bf*)(wihb + row * 256 + k * 32 + quad * 8);
      BHH[nt][k] = *(const v8bf*)(whhb + row * 256 + k * 32 + quad * 8);
    }
  }
  __syncthreads();

  for (int t = 0; t < T_FRAMES; t++) {
    // prefetch this step's full A/v tile (bf16, 7 rows x 8 cols per thread);
    // flies during the h wait
    v8bf aR[7], vR[7];
    #pragma unroll
    for (int rr = 0; rr < 7; rr++) {
      int i = r8 * 7 + rr;
      long off = ((long)t * NI + ((i < NI) ? i : NI - 1)) * HID + c32 * 8;
      aR[rr] = *(const v8bf*)(Abf + off);
      vR[rr] = *(const v8bf*)(vbf + off);
    }

    if (t > 0) {  // ---- the single hop: wait for h_t ----
      if (wv == 0 && !dead) {
        const unsigned tgt = (unsigned)t;
        int guard = 0;
        while (true) {
          unsigned fv = (lane < NWG)
              ? __hip_atomic_load(&flh[lane * 32], __ATOMIC_ACQUIRE, __HIP_MEMORY_SCOPE_AGENT)
              : tgt;
          if (__all(fv >= tgt)) break;
          if (++guard > POLL_MAX) { dead = 1; break; }
        }
      }
      __syncthreads();  // B0
      float hv = __hip_atomic_load(&hbuf[tid], __ATOMIC_RELAXED, __HIP_MEMORY_SCOPE_AGENT);
      hs[tid] = hv;
      hbf[tid] = (__bf16)hv;
      __syncthreads();  // B1
    }

    // stage s = tanh(A + h) bf16 into Ss (all 49 rows), v into Vs
    {
      float hr[8];
      #pragma unroll
      for (int e = 0; e < 8; e++) hr[e] = hs[c32 * 8 + e];
      #pragma unroll
      for (int rr = 0; rr < 7; rr++) {
        int i = r8 * 7 + rr;
        if (i < NI) {
          v8bf sv;
          #pragma unroll
          for (int e = 0; e < 8; e++)
            sv[e] = (__bf16)tanh_fast((float)aR[rr][e] + hr[e]);
          *(v8bf*)&Ss[i][c32 * 8] = sv;
          *(v8bf*)&Vs[i][c32 * 8] = vR[rr];
        }
      }
    }
    __syncthreads();  // B2

    // logits = s @ W2^T + b2: full 49(->64)x256 per WG, 128 MFMA/wave
    v4f acc[4][4];
    #pragma unroll
    for (int mt = 0; mt < 4; mt++)
      #pragma unroll
      for (int ntl = 0; ntl < 4; ntl++) acc[mt][ntl] = (v4f){0.f, 0.f, 0.f, 0.f};
    #pragma unroll
    for (int k = 0; k < 8; k++) {
      v8bf av[4];
      #pragma unroll
      for (int mt = 0; mt < 4; mt++)
        av[mt] = *(const v8bf*)&Ss[mt * 16 + l15][k * 32 + quad * 8];
      #pragma unroll
      for (int mt = 0; mt < 4; mt++)
        #pragma unroll
        for (int ntl = 0; ntl < 4; ntl++)
          acc[mt][ntl] = __builtin_amdgcn_mfma_f32_16x16x32_bf16(av[mt], BW2[ntl][k], acc[mt][ntl], 0, 0, 0);
    }
    #pragma unroll
    for (int mt = 0; mt < 4; mt++)
      #pragma unroll
      for (int ntl = 0; ntl < 4; ntl++) {
        const int col = wv * 64 + ntl * 16 + l15;
        const float bb = b2s[col];
        #pragma unroll
        for (int reg = 0; reg < 4; reg++) {
          int grow = mt * 16 + quad * 4 + reg;
          if (grow < NI) Wt[grow][col] = acc[mt][ntl][reg] + bb;
        }
      }
    __syncthreads();  // B3

    // softmax rows (wave wv: rows wv, wv+4, ...) fused with ctx partial accumulate
    {
      float cacc[4] = {0.f, 0.f, 0.f, 0.f};
      for (int i = wv; i < NI; i += 4) {
        float x[4];
        #pragma unroll
        for (int j = 0; j < 4; j++) x[j] = Wt[i][lane + 64 * j];
        float m = fmaxf(fmaxf(x[0], x[1]), fmaxf(x[2], x[3]));
        #pragma unroll
        for (int off = 32; off; off >>= 1) m = fmaxf(m, __shfl_xor(m, off, 64));
        float e[4], sm = 0.f;
        #pragma unroll
        for (int j = 0; j < 4; j++) { e[j] = __expf(x[j] - m); sm += e[j]; }
        #pragma unroll
        for (int off = 32; off; off >>= 1) sm += __shfl_xor(sm, off, 64);
        const float inv = 1.f / sm;
        #pragma unroll
        for (int j = 0; j < 4; j++)
          cacc[j] += e[j] * inv * (float)Vs[i][lane + 64 * j];
      }
      #pragma unroll
      for (int j = 0; j < 4; j++) ctxp[wv][lane + 64 * j] = cacc[j];
    }
    __syncthreads();  // B4

    // full ctx locally (no exchange!)
    {
      float cx = ctxp[0][tid] + ctxp[1][tid] + ctxp[2][tid] + ctxp[3][tid];
      cxbf[tid] = (__bf16)cx;
    }
    __syncthreads();  // B5

    // gates = ctx@Wih^T + h@Whh^T for my 32 dims (M=1 MFMA)
    v4f gacc[2];
    gacc[0] = (v4f){0.f, 0.f, 0.f, 0.f};
    gacc[1] = (v4f){0.f, 0.f, 0.f, 0.f};
    #pragma unroll
    for (int k = 0; k < 8; k++) {
      v8bf cf, hf;
      #pragma unroll
      for (int z = 0; z < 8; z++) { cf[z] = (__bf16)0.f; hf[z] = (__bf16)0.f; }
      if (l15 == 0) {
        cf = *(const v8bf*)&cxbf[k * 32 + quad * 8];
        hf = *(const v8bf*)&hbf[k * 32 + quad * 8];
      }
      gacc[0] = __builtin_amdgcn_mfma_f32_16x16x32_bf16(cf, BIH[0][k], gacc[0], 0, 0, 0);
      gacc[0] = __builtin_amdgcn_mfma_f32_16x16x32_bf16(hf, BHH[0][k], gacc[0], 0, 0, 0);
      gacc[1] = __builtin_amdgcn_mfma_f32_16x16x32_bf16(cf, BIH[1][k], gacc[1], 0, 0, 0);
      gacc[1] = __builtin_amdgcn_mfma_f32_16x16x32_bf16(hf, BHH[1][k], gacc[1], 0, 0, 0);
    }
    #pragma unroll
    for (int nt = 0; nt < 2; nt++) {
      float tot = gacc[nt][0] + gacc[nt][1] + gacc[nt][2] + gacc[nt][3];
      tot += __shfl_xor(tot, 16, 64);
      tot += __shfl_xor(tot, 32, 64);
      if (lane < 16) gb[wv][nt * 16 + lane] = tot;
    }
    __syncthreads();  // B6

    // cell update; publish my h slice (drain via syncthreads, then release flag)
    if (tid < 32) {
      float gi = gb[0][tid] + cbias[0];
      float gf = gb[1][tid] + cbias[1];
      float gg = gb[2][tid] + cbias[2];
      float go = gb[3][tid] + cbias[3];
      float si = 1.f / (1.f + __expf(-gi));
      float sf = 1.f / (1.f + __expf(-gf));
      float so = 1.f / (1.f + __expf(-go));
      creg = sf * creg + si * tanh_fast(gg);
      float hn = so * tanh_fast(creg);
      __hip_atomic_store(&hbuf[32 * w + tid], hn, __ATOMIC_RELAXED, __HIP_MEMORY_SCOPE_AGENT);
    }
    __syncthreads();  // B7 (drains the h stores)
    if (tid == 0)
      __hip_atomic_store(&flh[w * 32], (unsigned)(t + 1), __ATOMIC_RELEASE, __HIP_MEMORY_SCOPE_AGENT);
  }

  // q = h_T @ q_w^T + q_b
  if (w == 0) {
    if (wv == 0 && !dead) {
      const unsigned tgt = (unsigned)T_FRAMES;
      int guard = 0;
      while (true) {
        unsigned fv = (lane < NWG)
            ? __hip_atomic_load(&flh[lane * 32], __ATOMIC_ACQUIRE, __HIP_MEMORY_SCOPE_AGENT)
            : tgt;
        if (__all(fv >= tgt)) break;
        if (++guard > POLL_MAX) { dead = 1; break; }
      }
    }
    __syncthreads();
    hs[tid] = __hip_atomic_load(&hbuf[tid], __ATOMIC_RELAXED, __HIP_MEMORY_SCOPE_AGENT);
    __syncthreads();
    if (tid < NA) {
      float acc = qb[tid];
      for (int k = 0; k < HID; k++) acc += hs[k] * qw[tid * HID + k];
      out[tid] = acc;
    }
  }
}

extern "C" void kernel_launch(void* const* d_in, const int* in_sizes, int n_in,
                              void* d_out, int out_size, void* d_ws, size_t ws_size,
                              hipStream_t stream) {
  const float* frames = (const float*)d_in[0];
  const float* c1w = (const float*)d_in[1];
  const float* c1b = (const float*)d_in[2];
  const float* c2w = (const float*)d_in[3];
  const float* c2b = (const float*)d_in[4];
  const float* c3w = (const float*)d_in[5];
  const float* c3b = (const float*)d_in[6];
  const float* aw1 = (const float*)d_in[7];
  const float* ab1 = (const float*)d_in[8];
  const float* aw2 = (const float*)d_in[9];
  const float* ab2 = (const float*)d_in[10];
  const float* wih = (const float*)d_in[11];
  const float* whh = (const float*)d_in[12];
  const float* bih = (const float*)d_in[13];
  const float* bhh = (const float*)d_in[14];
  const float* qw  = (const float*)d_in[15];
  const float* qb  = (const float*)d_in[16];

  char* ws = (char*)d_ws;
  float*  fm1   = (float*)(ws + OFF_FM1);
  __bf16* Abf   = (__bf16*)(ws + OFF_ABF);   // alias: fm1 dead after conv2
  __bf16* vbf   = (__bf16*)(ws + OFF_VBF);   // alias: fm1 dead after conv2
  float*  fm2   = (float*)(ws + OFF_FM2);
  float*  vecs  = (float*)(ws + OFF_VECS);
  __bf16* w2b   = (__bf16*)(ws + OFF_W2B);
  __bf16* wihb  = (__bf16*)(ws + OFF_WIHB);
  __bf16* whhb  = (__bf16*)(ws + OFF_WHHB);
  float*  w1t   = (float*)(ws + OFF_W1T);
  float*    hbuf = (float*)(ws + OFF_HBUF);  // aliases fm2 (dead after conv3)
  unsigned* flh  = (unsigned*)(ws + OFF_FLH);

  prep_weights<<<256, 256, 0, stream>>>(aw2, wih, whh, aw1, w2b, wihb, whhb, w1t);
  conv1_k<<<102400, 256, 0, stream>>>(frames, c1w, c1b, fm1);
  conv2_k<<<T_FRAMES, 256, 0, stream>>>(fm1, c2w, c2b, fm2);
  conv3_k<<<T_FRAMES, 256, 0, stream>>>(fm2, c3w, c3b, vecs, vbf);
  aprep_k<<<T_FRAMES, 256, 0, stream>>>(vecs, w1t, ab1, Abf);
  init_comm<<<1, 256, 0, stream>>>(flh);  // after conv3: comm aliases fm2
  scan_k<<<NWG, 256, 0, stream>>>(Abf, vbf, w2b, wihb, whhb, ab2, bih, bhh, qw, qb,
                                  hbuf, flh, (float*)d_out);
}